// Round 8
// baseline (236.233 us; speedup 1.0000x reference)
//
#include <hip/hip_runtime.h>

#define NODE 400
#define POP 3
#define TRS 40
#define STEPS 10
#define DMAX 500
#define OUT 64
#define DT 0.1f
#define JPL 7            // ceil(NODE/64) j-indices per lane
#define WSTR 576         // per-stream W bin stride (>= 63 + DMAX-1 + 1)
#define NTOT (NODE * NODE)
#define SBSZ (DMAX + 448) // history: hE (reversed) + sim steps (chunk-flushed)
#define TTOT (TRS * STEPS)

__device__ __forceinline__ float relu_(float x) { return x > 0.f ? x : 0.f; }
__device__ __forceinline__ float rcp_(float x) { return __builtin_amdgcn_rcpf(x); }
__device__ __forceinline__ float rlane_(float v, int l) {
  return __builtin_bit_cast(float, __builtin_amdgcn_readlane(__builtin_bit_cast(int, v), l));
}

template <int CTRL>
__device__ __forceinline__ float dpp_mov(float x) {
  int r = __builtin_amdgcn_update_dpp(0, __builtin_bit_cast(int, x), CTRL,
                                      0xf, 0xf, true);
  return __builtin_bit_cast(float, r);
}
template <int CTRL>
__device__ __forceinline__ int dpp_movi(int x) {
  return __builtin_amdgcn_update_dpp(0, x, CTRL, 0xf, 0xf, true);
}
// wave_ror:1 (0x13C): lane n receives lane (n-1)&63's value.
__device__ __forceinline__ float ror1_(float x) { return dpp_mov<0x13C>(x); }

__device__ __forceinline__ void wave_reduce3(float& a, float& b, float& c) {
  a += dpp_mov<0x111>(a); b += dpp_mov<0x111>(b); c += dpp_mov<0x111>(c);
  a += dpp_mov<0x112>(a); b += dpp_mov<0x112>(b); c += dpp_mov<0x112>(c);
  a += dpp_mov<0x114>(a); b += dpp_mov<0x114>(b); c += dpp_mov<0x114>(c);
  a += dpp_mov<0x118>(a); b += dpp_mov<0x118>(b); c += dpp_mov<0x118>(c);
  a += dpp_mov<0x142>(a); b += dpp_mov<0x142>(b); c += dpp_mov<0x142>(c);
  a += dpp_mov<0x143>(a); b += dpp_mov<0x143>(b); c += dpp_mov<0x143>(c);
  a = rlane_(a, 63); b = rlane_(b, 63); c = rlane_(c, 63);
}
__device__ __forceinline__ float wave_reduce1(float a) {
  a += dpp_mov<0x111>(a);
  a += dpp_mov<0x112>(a);
  a += dpp_mov<0x114>(a);
  a += dpp_mov<0x118>(a);
  a += dpp_mov<0x142>(a);
  a += dpp_mov<0x143>(a);
  return rlane_(a, 63);
}
__device__ __forceinline__ int wave_max_int(int x) {
  x = max(x, dpp_movi<0x111>(x));
  x = max(x, dpp_movi<0x112>(x));
  x = max(x, dpp_movi<0x114>(x));
  x = max(x, dpp_movi<0x118>(x));
  x = max(x, dpp_movi<0x142>(x));
  x = max(x, dpp_movi<0x143>(x));
  return __builtin_amdgcn_readlane(x, 63);
}

// ---------------------------------------------------------------------------
// ONE fused kernel, ZERO memory ops in the per-step loop:
//  - binning phase also produces row sum-of-squares (no separate ssq pass)
//  - u(t) preloaded to VGPRs UL[0..6]; fetched via readlane (same idx as AL)
//  - s(t) captured per-lane via cndmask (sP is wave-uniform -> lane i keeps
//    its copy); ONE ds_write per 64-step chunk; refill is the only reader
//  - V2 snapshots captured via cndmask into VS; one global store post-loop
//  - norm scalars folded into the LDS W bins once (harvest is pre-scaled)
// Static per-lane partials AL[lane] (lane owns steps == lane mod 64);
// rotating scatter weights via one independent wave_ror:1 per stream.
// ---------------------------------------------------------------------------
__global__ __launch_bounds__(64) void fused_kernel(
    const float* __restrict__ external, const float* __restrict__ hx,
    const float* __restrict__ hE, const float* __restrict__ sc,
    const float* __restrict__ dist, const float* __restrict__ wbb,
    const float* __restrict__ wff, const float* __restrict__ wll,
    const float* __restrict__ lm, const float* __restrict__ theta,
    unsigned* __restrict__ bar, float* __restrict__ part,
    float* __restrict__ vsnap, float* __restrict__ out) {
  const int node = blockIdx.x;
  const int lane = threadIdx.x;

  __shared__ float Wall[3 * WSTR];  // Wl | Wf | Wb delay bins (zero-padded)
  __shared__ float SB[SBSZ];        // SB[i]=hE[DMAX-1-i] i<DMAX; SB[DMAX+t]=s(t)

  // --- parameters ---
  const float VL = relu_(theta[0]), VI = relu_(theta[1]);
  const float VE = relu_(theta[2]), VNMDA = relu_(theta[3]);
  const float alpha_mg = relu_(theta[4]), VR = relu_(theta[5]);
  const float pi_sigma = relu_(theta[6]);
  const float gLp = relu_(theta[7]), Cc = relu_(theta[8]), kappa = relu_(theta[9]);
  const float g_gE = relu_(theta[10]), g_gE_sc = relu_(theta[11]);
  const float g_gI = relu_(theta[12]), g_gI_sc = relu_(theta[13]);
  const float g_gN = relu_(theta[14]), g_gN_sc = relu_(theta[15]);
  const float g_k = relu_(theta[16]);
  const float y0v = theta[19];
  const float mu = 0.1f + relu_(theta[20]);
  const float uk = relu_(theta[21]) * theta[23];
  const float cy0 = theta[22];
  const float g_l = relu_(theta[24]), g_f = relu_(theta[25]), g_b = relu_(theta[26]);
  const float DTC = DT / Cc;
  const float dk = DT * kappa;
  const float nps = -pi_sigma, psVR = pi_sigma * VR;
  const float nam = -alpha_mg;
  const float dk1 = 1.f - dk;
  const float gLVL = gLp * VL;
  const float ukdk = dk * uk;

  // --- stage LDS (single wave: LDS ops in program order) ---
  for (int k = lane; k < 3 * WSTR; k += 64) Wall[k] = 0.f;
  for (int d = lane; d < DMAX; d += 64) SB[DMAX - 1 - d] = hE[node * DMAX + d];

  // --- phase 1: bin RAW weights by delay; row sums; row sum-of-squares ---
  float rl = 0.f, rf = 0.f, rb = 0.f;       // row sums
  float ql = 0.f, qf = 0.f, qb = 0.f;       // row sums of squares
  int mymax = 0;
#pragma unroll
  for (int kj = 0; kj < JPL; ++kj) {
    int j = lane + kj * 64;
    if (j < NODE) {
      int ij = node * NODE + j;
      int ji = j * NODE + node;
      float scij = sc[ij];
      float vb = __expf(wbb[ij]) * scij;
      float vf = __expf(wff[ij]) * scij;
      float vl = 0.5f * (__expf(wll[ij]) * scij + __expf(wll[ji]) * sc[ji]);
      int dd = (int)(dist[ij] / mu);
      dd = min(max(dd, 0), DMAX - 1);
      atomicAdd(&Wall[dd], vl);
      atomicAdd(&Wall[WSTR + dd], vf);
      atomicAdd(&Wall[2 * WSTR + dd], vb);
      rl += vl; rf += vf; rb += vb;
      ql = fmaf(vl, vl, ql); qf = fmaf(vf, vf, qf); qb = fmaf(vb, vb, qb);
      mymax = max(mymax, dd);
    }
  }
  {
    float a = qb, b = qf, c2 = ql;
    wave_reduce3(a, b, c2);
    if (lane == 0) {
      part[node] = a; part[NODE + node] = b; part[2 * NODE + node] = c2;
    }
  }
  __threadfence();
  if (lane == 0) atomicAdd(&bar[0], 1u);
  wave_reduce3(rl, rf, rb);                 // raw row sums (all lanes)
  const int maxd = wave_max_int(mymax);

  // --- init AL with RAW bins (overlaps other blocks' binning) ---
  // AL[l] (raw) = sum_r W[l+r] * hE[r], hE[r] = SB[DMAX-1-r]
  float ALl = 0.f, ALf = 0.f, ALb = 0.f;
  for (int r = 0; r <= maxd; ++r) {
    float h = SB[DMAX - 1 - r];             // uniform -> broadcast
    int d = lane + r;                        // < 63+500 < WSTR
    ALl = fmaf(Wall[d], h, ALl);
    ALf = fmaf(Wall[WSTR + d], h, ALf);
    ALb = fmaf(Wall[2 * WSTR + d], h, ALb);
  }

  // --- preload u into registers: UL[k] lane l = dk*uk*u(t=64k+l) ---
  float UL[7];
#pragma unroll
  for (int k = 0; k < 7; ++k) {
    int t = (k << 6) + lane;
    float v = 0.f;
    if (t < TTOT) {
      int tr_ = t / STEPS, st_ = t - tr_ * STEPS;
      v = ukdk * external[node * TTOT + st_ * TRS + tr_];
    }
    UL[k] = v;
  }

  // --- initial state (replicated) ---
  const int hb = node * POP * 4;
  float V0 = hx[hb + 0], V1 = hx[hb + 4], V2 = hx[hb + 8];
  float E0 = hx[hb + 1], E1 = hx[hb + 5], E2 = hx[hb + 9];
  float I0 = hx[hb + 2], I1 = hx[hb + 6], I2 = hx[hb + 10];
  float N0 = hx[hb + 3], N1 = hx[hb + 7], N2 = hx[hb + 11];

  // --- wait for global ssq; compute norms; fold into bins and AL ---
  while (__hip_atomic_load(&bar[0], __ATOMIC_ACQUIRE,
                           __HIP_MEMORY_SCOPE_AGENT) < (unsigned)NODE)
    __builtin_amdgcn_s_sleep(2);
  __threadfence();
  float VS = 0.f;      // V2 snapshots, lane = trial id (captured via cndmask)
  {
    float sb = 0.f, sf = 0.f, sl = 0.f;
#pragma unroll
    for (int jj = 0; jj < JPL; ++jj) {
      int i = lane + (jj << 6);
      if (i < NODE) {
        sb += part[i]; sf += part[NODE + i]; sl += part[2 * NODE + i];
      }
    }
    wave_reduce3(sb, sf, sl);
    const float inv_nb_ = 1.f / sqrtf(sb);
    const float inv_nf_ = 1.f / sqrtf(sf);
    const float inv_nl_ = 1.f / sqrtf(sl);
    const float cA2 = dk * g_l * inv_nl_;     // fold into l-bins
    const float cF2 = dk * g_f * inv_nf_;     // fold into f-bins
    const float cB2 = dk * g_b * inv_nb_;     // fold into b-bins
    const float rs_l = inv_nl_ * rl, rs_f = inv_nf_ * rf, rs_b = inv_nb_ * rb;
    const float cE0s2 = dk * g_gE - dk * g_l * rs_l;
    const float cN0s2 = dk * g_gN - dk * g_l * rs_l;
    const float cE1s = -(dk * g_b) * rs_b;
    const float cE2s = -(dk * g_f) * rs_f;
    const float cE1e = dk * g_gE_sc, cE2e = dk * g_k;
    const float cI0 = dk * g_gI, cI1 = dk * g_gI_sc;
    const float cN1 = dk * g_gN_sc, cN2 = dk * g_gN;

    // scale bins in place (single wave, in order)
    for (int k = lane; k < WSTR; k += 64) {
      Wall[k] *= cA2;
      Wall[WSTR + k] *= cF2;
      Wall[2 * WSTR + k] *= cB2;
    }
    ALl *= cA2; ALf *= cF2; ALb *= cB2;

    // rotating scatter weights (scaled): omega(l, t=0) = W[(l-1) & 63]
    const int w0i = (lane + 63) & 63;
    float wql = Wall[w0i], wqf = Wall[WSTR + w0i], wqb = Wall[2 * WSTR + w0i];

    int stepc = STEPS, tr = 0;

    // --- main loop: 7 chunks of 64 steps (last = 16); NO memory ops/step ---
#pragma unroll
    for (int c = 0; c < 7; ++c) {
      float SH = 0.f;                        // s(64c + lane) collector
      if (c > 0) {
        const int t0 = c << 6;
        for (int d = 64; d <= maxd; ++d) {   // delta>=64 refill (scaled bins)
          float w1 = Wall[d], w2 = Wall[WSTR + d], w3 = Wall[2 * WSTR + d];
          float s = SB[DMAX + t0 - 1 - d + lane];
          ALl = fmaf(w1, s, ALl);
          ALf = fmaf(w2, s, ALf);
          ALb = fmaf(w3, s, ALb);
        }
      }
      const int tend = (c == 6) ? (TTOT - 384) : 64;
#pragma unroll 1
      for (int i = 0; i < tend; ++i) {
        // 1) harvest (pre-scaled): t1/t2/t3 + this step's u
        float t1 = rlane_(ALl, i);
        float t2 = rlane_(ALf, i);
        float t3 = rlane_(ALb, i);
        float U  = rlane_(UL[c], i);

        // 2) dynamics (replicated)
        float sE = rcp_(1.f + __expf(fmaf(nps, V0, psVR)));
        float sI = rcp_(1.f + __expf(fmaf(nps, V1, psVR)));
        float sP = rcp_(1.f + __expf(fmaf(nps, V2, psVR)));
        float m0 = rcp_(fmaf(0.2f, __expf(nam * V0), 1.f));
        float m1 = rcp_(fmaf(0.2f, __expf(nam * V1), 1.f));
        float m2 = rcp_(fmaf(0.2f, __expf(nam * V2), 1.f));

        float nE0 = fmaf(dk1, E0, fmaf(cE0s2, sP, t1 + U));
        float nE1 = fmaf(dk1, E1, fmaf(cE1e, sE, fmaf(cE1s, sP, t3)));
        float nE2 = fmaf(dk1, E2, fmaf(cE2e, sE, fmaf(cE2s, sP, t2 + U)));
        float pI = cI0 * sI;
        float nI0 = fmaf(dk1, I0, pI);
        float nI1 = fmaf(dk1, I1, cI1 * sI);
        float nI2 = fmaf(dk1, I2, pI);
        float nN0 = fmaf(dk1, N0, fmaf(cN0s2, sP, t1));
        float nN1 = fmaf(dk1, N1, cN1 * sE);
        float nN2 = fmaf(dk1, N2, cN2 * sE);

        float Nm0 = N0 * m0, Nm1 = N1 * m1, Nm2 = N2 * m2;
        float R0 = fmaf(E0, VE, fmaf(Nm0, VNMDA, fmaf(I0, -VI, -gLVL)));
        float R1 = fmaf(E1, VE, fmaf(Nm1, VNMDA, fmaf(I1, -VI, -gLVL)));
        float R2 = fmaf(E2, VE, fmaf(Nm2, VNMDA, fmaf(I2, -VI, -gLVL)));
        float S0 = gLp + E0 + I0 + Nm0;
        float S1 = gLp + E1 + I1 + Nm1;
        float S2 = gLp + E2 + I2 + Nm2;
        V0 = fmaf(DTC, fmaf(-S0, V0, R0), V0);
        V1 = fmaf(DTC, fmaf(-S1, V1, R1), V1);
        V2 = fmaf(DTC, fmaf(-S2, V2, R2), V2);
        E0 = nE0; E1 = nE1; E2 = nE2;
        I0 = nI0; I1 = nI1; I2 = nI2;
        N0 = nN0; N1 = nN1; N2 = nN2;

        // 3) consume-reset + scatter (rotating per-lane weights, scaled)
        bool cons = (lane == i);
        ALl = fmaf(wql, sP, cons ? 0.f : ALl);
        ALf = fmaf(wqf, sP, cons ? 0.f : ALf);
        ALb = fmaf(wqb, sP, cons ? 0.f : ALb);
        wql = ror1_(wql); wqf = ror1_(wqf); wqb = ror1_(wqb);

        // 4) capture s(t): sP is wave-uniform, lane i keeps its copy
        SH = cons ? sP : SH;

        // 5) branchless trial-boundary V2 snapshot (V2 wave-uniform)
        bool tb = (stepc == 1);
        VS = (tb && lane == tr) ? V2 : VS;
        stepc = tb ? STEPS : stepc - 1;
        tr += tb;
      }
      if (c < 6) SB[DMAX + (c << 6) + lane] = SH;  // one ds_write per chunk
    }
  }

  // --- flush V2 snapshots; signal; eeg readout on blocks 0..TRS-1 ---
  if (lane < TRS) vsnap[lane * NODE + node] = VS;
  __threadfence();
  if (lane == 0) atomicAdd(&bar[1], 1u);
  if (node < TRS) {
    while (__hip_atomic_load(&bar[1], __ATOMIC_ACQUIRE,
                             __HIP_MEMORY_SCOPE_AGENT) < (unsigned)NODE)
      __builtin_amdgcn_s_sleep(2);
    __threadfence();
    const float* vs = vsnap + node * NODE;
    const float* lr = lm + lane * NODE;
    float d0 = 0.f, d1 = 0.f, d2 = 0.f, d3 = 0.f;
    for (int n = 0; n < NODE; n += 4) {
      d0 = fmaf(lr[n], vs[n], d0);
      d1 = fmaf(lr[n + 1], vs[n + 1], d1);
      d2 = fmaf(lr[n + 2], vs[n + 2], d2);
      d3 = fmaf(lr[n + 3], vs[n + 3], d3);
    }
    float dot = (d0 + d1) + (d2 + d3);
    float tot = wave_reduce1(dot);       // sum over o (lanes)
    out[node * OUT + lane] = fmaf(cy0, dot - tot * (1.f / OUT), -y0v);
  }
}

extern "C" void kernel_launch(void* const* d_in, const int* in_sizes, int n_in,
                              void* d_out, int out_size, void* d_ws, size_t ws_size,
                              hipStream_t stream) {
  const float* external = (const float*)d_in[0];
  const float* hx       = (const float*)d_in[1];
  const float* hE       = (const float*)d_in[2];
  const float* sc       = (const float*)d_in[3];
  const float* dist     = (const float*)d_in[4];
  const float* wbb      = (const float*)d_in[5];
  const float* wff      = (const float*)d_in[6];
  const float* wll      = (const float*)d_in[7];
  const float* lm       = (const float*)d_in[8];
  const float* theta    = (const float*)d_in[9];
  float* out = (float*)d_out;

  unsigned* bar = (unsigned*)d_ws;                 // [0],[1] barrier counters
  float* part  = (float*)d_ws + 4;                 // 3*NODE ssq partials
  float* vsnap = part + 3 * NODE;                  // TRS*NODE V2 snapshots

  (void)hipMemsetAsync(d_ws, 0, 16, stream);       // zero the two counters
  fused_kernel<<<NODE, 64, 0, stream>>>(external, hx, hE, sc, dist, wbb, wff,
                                        wll, lm, theta, bar, part, vsnap, out);
}

// Round 9
// 221.506 us; speedup vs baseline: 1.0665x; 1.0665x over previous
//
#include <hip/hip_runtime.h>

#define NODE 400
#define POP 3
#define TRS 40
#define STEPS 10
#define DMAX 500
#define OUT 64
#define DT 0.1f
#define JPL 7            // ceil(NODE/64) j-indices per lane
#define WSTR 576         // per-stream W bin stride (>= 63 + DMAX-1 + 1)
#define NTOT (NODE * NODE)
#define SBSZ (DMAX + 448) // history: hE (reversed) + sim steps (chunk-flushed)
#define TTOT (TRS * STEPS)

__device__ __forceinline__ float relu_(float x) { return x > 0.f ? x : 0.f; }
__device__ __forceinline__ float rcp_(float x) { return __builtin_amdgcn_rcpf(x); }
__device__ __forceinline__ float rlane_(float v, int l) {
  return __builtin_bit_cast(float, __builtin_amdgcn_readlane(__builtin_bit_cast(int, v), l));
}

template <int CTRL>
__device__ __forceinline__ float dpp_mov(float x) {
  int r = __builtin_amdgcn_update_dpp(0, __builtin_bit_cast(int, x), CTRL,
                                      0xf, 0xf, true);
  return __builtin_bit_cast(float, r);
}
template <int CTRL>
__device__ __forceinline__ int dpp_movi(int x) {
  return __builtin_amdgcn_update_dpp(0, x, CTRL, 0xf, 0xf, true);
}
// wave_ror:1 (0x13C): lane n receives lane (n-1)&63's value.
__device__ __forceinline__ float ror1_(float x) { return dpp_mov<0x13C>(x); }

__device__ __forceinline__ void wave_reduce3(float& a, float& b, float& c) {
  a += dpp_mov<0x111>(a); b += dpp_mov<0x111>(b); c += dpp_mov<0x111>(c);
  a += dpp_mov<0x112>(a); b += dpp_mov<0x112>(b); c += dpp_mov<0x112>(c);
  a += dpp_mov<0x114>(a); b += dpp_mov<0x114>(b); c += dpp_mov<0x114>(c);
  a += dpp_mov<0x118>(a); b += dpp_mov<0x118>(b); c += dpp_mov<0x118>(c);
  a += dpp_mov<0x142>(a); b += dpp_mov<0x142>(b); c += dpp_mov<0x142>(c);
  a += dpp_mov<0x143>(a); b += dpp_mov<0x143>(b); c += dpp_mov<0x143>(c);
  a = rlane_(a, 63); b = rlane_(b, 63); c = rlane_(c, 63);
}
__device__ __forceinline__ float wave_reduce1(float a) {
  a += dpp_mov<0x111>(a);
  a += dpp_mov<0x112>(a);
  a += dpp_mov<0x114>(a);
  a += dpp_mov<0x118>(a);
  a += dpp_mov<0x142>(a);
  a += dpp_mov<0x143>(a);
  return rlane_(a, 63);
}
__device__ __forceinline__ int wave_max_int(int x) {
  x = max(x, dpp_movi<0x111>(x));
  x = max(x, dpp_movi<0x112>(x));
  x = max(x, dpp_movi<0x114>(x));
  x = max(x, dpp_movi<0x118>(x));
  x = max(x, dpp_movi<0x142>(x));
  x = max(x, dpp_movi<0x143>(x));
  return __builtin_amdgcn_readlane(x, 63);
}

// ---------------------------------------------------------------------------
// ONE fused kernel. Per-step loop: zero memory ops AND only TWO
// transcendentals — the 6 sigmoid/Mg evaluations are packed into lanes 0..5
// of one v_exp + one v_rcp (state is wave-uniform), extracted with 6
// constant-index readlanes. Coupling via static per-lane partials AL[lane]
// (lane owns steps == lane mod 64), rotating scatter weights (one wave_ror:1
// per stream), chunked history flush/refill. eeg uses a pre-transposed,
// colmean-folded lmT (built in phase 0) -> coalesced loads, no reduction.
// ---------------------------------------------------------------------------
__global__ __launch_bounds__(64) void fused_kernel(
    const float* __restrict__ external, const float* __restrict__ hx,
    const float* __restrict__ hE, const float* __restrict__ sc,
    const float* __restrict__ dist, const float* __restrict__ wbb,
    const float* __restrict__ wff, const float* __restrict__ wll,
    const float* __restrict__ lm, const float* __restrict__ theta,
    unsigned* __restrict__ bar, float* __restrict__ part,
    float* __restrict__ vsnap, float* __restrict__ lmT,
    float* __restrict__ out) {
  const int node = blockIdx.x;
  const int lane = threadIdx.x;

  __shared__ float Wall[3 * WSTR];  // Wl | Wf | Wb delay bins (zero-padded)
  __shared__ float SB[SBSZ];        // SB[i]=hE[DMAX-1-i] i<DMAX; SB[DMAX+t]=s(t)

  // --- parameters ---
  const float VL = relu_(theta[0]), VI = relu_(theta[1]);
  const float VE = relu_(theta[2]), VNMDA = relu_(theta[3]);
  const float alpha_mg = relu_(theta[4]), VR = relu_(theta[5]);
  const float pi_sigma = relu_(theta[6]);
  const float gLp = relu_(theta[7]), Cc = relu_(theta[8]), kappa = relu_(theta[9]);
  const float g_gE = relu_(theta[10]), g_gE_sc = relu_(theta[11]);
  const float g_gI = relu_(theta[12]), g_gI_sc = relu_(theta[13]);
  const float g_gN = relu_(theta[14]), g_gN_sc = relu_(theta[15]);
  const float g_k = relu_(theta[16]);
  const float y0v = theta[19];
  const float mu = 0.1f + relu_(theta[20]);
  const float uk = relu_(theta[21]) * theta[23];
  const float cy0 = theta[22];
  const float g_l = relu_(theta[24]), g_f = relu_(theta[25]), g_b = relu_(theta[26]);
  const float DTC = DT / Cc;
  const float dk = DT * kappa;
  const float nps = -pi_sigma, psVR = pi_sigma * VR;
  const float nam = -alpha_mg;
  const float dk1 = 1.f - dk;
  const float gLVL = gLp * VL;
  const float ukdk = dk * uk;

  // --- packed-transcendental per-lane constants (lanes 0-2: s, 3-5: m) ---
  const bool c1 = (lane == 1) | (lane == 4);
  const bool c2 = (lane == 2) | (lane == 5);
  const float caL = (lane < 3) ? nps : nam;
  const float cbL = (lane < 3) ? psVR : 0.f;
  const float cmL = (lane < 3) ? 1.f : 0.2f;

  // --- stage LDS (single wave: LDS ops in program order) ---
  for (int k = lane; k < 3 * WSTR; k += 64) Wall[k] = 0.f;
  for (int d = lane; d < DMAX; d += 64) SB[DMAX - 1 - d] = hE[node * DMAX + d];

  // --- lmT transpose with colmean folded: lmT[node*64+o] = lm[o][node]-mean ---
  {
    float lv = lm[lane * NODE + node];          // gather (once)
    float mean = wave_reduce1(lv) * (1.f / OUT);
    lmT[node * OUT + lane] = lv - mean;         // coalesced store
  }

  // --- phase 1: bin RAW weights by delay; row sums; row sum-of-squares ---
  float rl = 0.f, rf = 0.f, rb = 0.f;       // row sums
  float ql = 0.f, qf = 0.f, qb = 0.f;       // row sums of squares
  int mymax = 0;
#pragma unroll
  for (int kj = 0; kj < JPL; ++kj) {
    int j = lane + kj * 64;
    if (j < NODE) {
      int ij = node * NODE + j;
      int ji = j * NODE + node;
      float scij = sc[ij];
      float vb = __expf(wbb[ij]) * scij;
      float vf = __expf(wff[ij]) * scij;
      float vl = 0.5f * (__expf(wll[ij]) * scij + __expf(wll[ji]) * sc[ji]);
      int dd = (int)(dist[ij] / mu);
      dd = min(max(dd, 0), DMAX - 1);
      atomicAdd(&Wall[dd], vl);
      atomicAdd(&Wall[WSTR + dd], vf);
      atomicAdd(&Wall[2 * WSTR + dd], vb);
      rl += vl; rf += vf; rb += vb;
      ql = fmaf(vl, vl, ql); qf = fmaf(vf, vf, qf); qb = fmaf(vb, vb, qb);
      mymax = max(mymax, dd);
    }
  }
  {
    float a = qb, b = qf, c22 = ql;
    wave_reduce3(a, b, c22);
    if (lane == 0) {
      part[node] = a; part[NODE + node] = b; part[2 * NODE + node] = c22;
    }
  }
  __threadfence();
  if (lane == 0) atomicAdd(&bar[0], 1u);
  wave_reduce3(rl, rf, rb);                 // raw row sums (all lanes)
  const int maxd = wave_max_int(mymax);

  // --- init AL with RAW bins: AL[l] = sum_r W[l+r] * hE[r] ---
  float ALl = 0.f, ALf = 0.f, ALb = 0.f;
  for (int r = 0; r <= maxd; ++r) {
    float h = SB[DMAX - 1 - r];             // uniform -> broadcast
    int d = lane + r;                        // < 63+500 < WSTR
    ALl = fmaf(Wall[d], h, ALl);
    ALf = fmaf(Wall[WSTR + d], h, ALf);
    ALb = fmaf(Wall[2 * WSTR + d], h, ALb);
  }

  // --- preload u into registers: UL[k] lane l = dk*uk*u(t=64k+l) ---
  float UL[7];
#pragma unroll
  for (int k = 0; k < 7; ++k) {
    int t = (k << 6) + lane;
    float v = 0.f;
    if (t < TTOT) {
      int tr_ = t / STEPS, st_ = t - tr_ * STEPS;
      v = ukdk * external[node * TTOT + st_ * TRS + tr_];
    }
    UL[k] = v;
  }

  // --- initial state (replicated) ---
  const int hb = node * POP * 4;
  float V0 = hx[hb + 0], V1 = hx[hb + 4], V2 = hx[hb + 8];
  float E0 = hx[hb + 1], E1 = hx[hb + 5], E2 = hx[hb + 9];
  float I0 = hx[hb + 2], I1 = hx[hb + 6], I2 = hx[hb + 10];
  float N0 = hx[hb + 3], N1 = hx[hb + 7], N2 = hx[hb + 11];

  // --- wait for global ssq; compute norms; fold into bins and AL ---
  while (__hip_atomic_load(&bar[0], __ATOMIC_ACQUIRE,
                           __HIP_MEMORY_SCOPE_AGENT) < (unsigned)NODE)
    __builtin_amdgcn_s_sleep(2);
  __threadfence();
  float VS = 0.f;      // V2 snapshots, lane = trial id (captured via cndmask)
  {
    float sb = 0.f, sf = 0.f, sl = 0.f;
#pragma unroll
    for (int jj = 0; jj < JPL; ++jj) {
      int i = lane + (jj << 6);
      if (i < NODE) {
        sb += part[i]; sf += part[NODE + i]; sl += part[2 * NODE + i];
      }
    }
    wave_reduce3(sb, sf, sl);
    const float inv_nb_ = 1.f / sqrtf(sb);
    const float inv_nf_ = 1.f / sqrtf(sf);
    const float inv_nl_ = 1.f / sqrtf(sl);
    const float cA2 = dk * g_l * inv_nl_;     // fold into l-bins
    const float cF2 = dk * g_f * inv_nf_;     // fold into f-bins
    const float cB2 = dk * g_b * inv_nb_;     // fold into b-bins
    const float rs_l = inv_nl_ * rl, rs_f = inv_nf_ * rf, rs_b = inv_nb_ * rb;
    const float cE0s2 = dk * g_gE - dk * g_l * rs_l;
    const float cN0s2 = dk * g_gN - dk * g_l * rs_l;
    const float cE1s = -(dk * g_b) * rs_b;
    const float cE2s = -(dk * g_f) * rs_f;
    const float cE1e = dk * g_gE_sc, cE2e = dk * g_k;
    const float cI0 = dk * g_gI, cI1 = dk * g_gI_sc;
    const float cN1 = dk * g_gN_sc, cN2 = dk * g_gN;

    // scale bins in place (single wave, in order)
    for (int k = lane; k < WSTR; k += 64) {
      Wall[k] *= cA2;
      Wall[WSTR + k] *= cF2;
      Wall[2 * WSTR + k] *= cB2;
    }
    ALl *= cA2; ALf *= cF2; ALb *= cB2;

    // rotating scatter weights (scaled): omega(l, t=0) = W[(l-1) & 63]
    const int w0i = (lane + 63) & 63;
    float wql = Wall[w0i], wqf = Wall[WSTR + w0i], wqb = Wall[2 * WSTR + w0i];

    int stepc = STEPS, tr = 0;

    // --- main loop: 7 chunks of 64 steps (last = 16) ---
#pragma unroll
    for (int c = 0; c < 7; ++c) {
      float SH = 0.f;                        // s(64c + lane) collector
      if (c > 0) {
        const int t0 = c << 6;
        for (int d = 64; d <= maxd; ++d) {   // delta>=64 refill (scaled bins)
          float w1 = Wall[d], w2 = Wall[WSTR + d], w3 = Wall[2 * WSTR + d];
          float s = SB[DMAX + t0 - 1 - d + lane];
          ALl = fmaf(w1, s, ALl);
          ALf = fmaf(w2, s, ALf);
          ALb = fmaf(w3, s, ALb);
        }
      }
      const int tend = (c == 6) ? (TTOT - 384) : 64;
#pragma unroll 1
      for (int i = 0; i < tend; ++i) {
        // 1) harvest (pre-scaled) + this step's u
        float t1 = rlane_(ALl, i);
        float t2 = rlane_(ALf, i);
        float t3 = rlane_(ALb, i);
        float U  = rlane_(UL[c], i);

        // 2) packed transcendentals: lanes 0-2 -> s(V0..V2), 3-5 -> m(V0..V2)
        float Vsel = c1 ? V1 : V0;
        Vsel = c2 ? V2 : Vsel;
        float ex = __expf(fmaf(caL, Vsel, cbL));
        float sm = rcp_(fmaf(cmL, ex, 1.f));
        float sE = rlane_(sm, 0), sI = rlane_(sm, 1), sP = rlane_(sm, 2);
        float m0 = rlane_(sm, 3), m1 = rlane_(sm, 4), m2 = rlane_(sm, 5);

        // 3) conductance updates (replicated; constants pre-folded)
        float nE0 = fmaf(dk1, E0, fmaf(cE0s2, sP, t1 + U));
        float nE1 = fmaf(dk1, E1, fmaf(cE1e, sE, fmaf(cE1s, sP, t3)));
        float nE2 = fmaf(dk1, E2, fmaf(cE2e, sE, fmaf(cE2s, sP, t2 + U)));
        float pI = cI0 * sI;
        float nI0 = fmaf(dk1, I0, pI);
        float nI1 = fmaf(dk1, I1, cI1 * sI);
        float nI2 = fmaf(dk1, I2, pI);
        float nN0 = fmaf(dk1, N0, fmaf(cN0s2, sP, fmaf(cA2, 0.f, t1)));
        float nN1 = fmaf(dk1, N1, cN1 * sE);
        float nN2 = fmaf(dk1, N2, cN2 * sE);

        // 4) membrane updates
        float Nm0 = N0 * m0, Nm1 = N1 * m1, Nm2 = N2 * m2;
        float R0 = fmaf(E0, VE, fmaf(Nm0, VNMDA, fmaf(I0, -VI, -gLVL)));
        float R1 = fmaf(E1, VE, fmaf(Nm1, VNMDA, fmaf(I1, -VI, -gLVL)));
        float R2 = fmaf(E2, VE, fmaf(Nm2, VNMDA, fmaf(I2, -VI, -gLVL)));
        float S0 = gLp + E0 + I0 + Nm0;
        float S1 = gLp + E1 + I1 + Nm1;
        float S2 = gLp + E2 + I2 + Nm2;
        V0 = fmaf(DTC, fmaf(-S0, V0, R0), V0);
        V1 = fmaf(DTC, fmaf(-S1, V1, R1), V1);
        V2 = fmaf(DTC, fmaf(-S2, V2, R2), V2);
        E0 = nE0; E1 = nE1; E2 = nE2;
        I0 = nI0; I1 = nI1; I2 = nI2;
        N0 = nN0; N1 = nN1; N2 = nN2;

        // 5) consume-reset + scatter (rotating per-lane weights, scaled)
        bool cons = (lane == i);
        ALl = fmaf(wql, sP, cons ? 0.f : ALl);
        ALf = fmaf(wqf, sP, cons ? 0.f : ALf);
        ALb = fmaf(wqb, sP, cons ? 0.f : ALb);
        wql = ror1_(wql); wqf = ror1_(wqf); wqb = ror1_(wqb);

        // 6) capture s(t): sP is uniform, lane i keeps its copy
        SH = cons ? sP : SH;

        // 7) branchless trial-boundary V2 snapshot (V2 wave-uniform)
        bool tb = (stepc == 1);
        VS = (tb && lane == tr) ? V2 : VS;
        stepc = tb ? STEPS : stepc - 1;
        tr += tb;
      }
      if (c < 6) SB[DMAX + (c << 6) + lane] = SH;  // one ds_write per chunk
    }
  }

  // --- flush V2 snapshots; signal; eeg readout on blocks 0..TRS-1 ---
  if (lane < TRS) vsnap[lane * NODE + node] = VS;
  __threadfence();
  if (lane == 0) atomicAdd(&bar[1], 1u);
  if (node < TRS) {
    while (__hip_atomic_load(&bar[1], __ATOMIC_ACQUIRE,
                             __HIP_MEMORY_SCOPE_AGENT) < (unsigned)NODE)
      __builtin_amdgcn_s_sleep(2);
    __threadfence();
    const float* vs = vsnap + node * NODE;   // this block's trial row
    float a0 = 0.f, a1 = 0.f, a2 = 0.f, a3 = 0.f;
    for (int n = 0; n < NODE; n += 4) {
      // lmT loads are coalesced (lane = o); vs loads are uniform broadcasts
      a0 = fmaf(lmT[(n + 0) * OUT + lane], vs[n + 0], a0);
      a1 = fmaf(lmT[(n + 1) * OUT + lane], vs[n + 1], a1);
      a2 = fmaf(lmT[(n + 2) * OUT + lane], vs[n + 2], a2);
      a3 = fmaf(lmT[(n + 3) * OUT + lane], vs[n + 3], a3);
    }
    float dot = (a0 + a1) + (a2 + a3);       // colmean already folded in lmT
    out[node * OUT + lane] = fmaf(cy0, dot, -y0v);
  }
}

extern "C" void kernel_launch(void* const* d_in, const int* in_sizes, int n_in,
                              void* d_out, int out_size, void* d_ws, size_t ws_size,
                              hipStream_t stream) {
  const float* external = (const float*)d_in[0];
  const float* hx       = (const float*)d_in[1];
  const float* hE       = (const float*)d_in[2];
  const float* sc       = (const float*)d_in[3];
  const float* dist     = (const float*)d_in[4];
  const float* wbb      = (const float*)d_in[5];
  const float* wff      = (const float*)d_in[6];
  const float* wll      = (const float*)d_in[7];
  const float* lm       = (const float*)d_in[8];
  const float* theta    = (const float*)d_in[9];
  float* out = (float*)d_out;

  unsigned* bar = (unsigned*)d_ws;                 // [0],[1] barrier counters
  float* part  = (float*)d_ws + 4;                 // 3*NODE ssq partials
  float* vsnap = part + 3 * NODE;                  // TRS*NODE V2 snapshots
  float* lmT   = vsnap + TRS * NODE;               // NODE*OUT colmean-folded

  (void)hipMemsetAsync(d_ws, 0, 16, stream);       // zero the two counters
  fused_kernel<<<NODE, 64, 0, stream>>>(external, hx, hE, sc, dist, wbb, wff,
                                        wll, lm, theta, bar, part, vsnap, lmT,
                                        out);
}